// Round 3
// baseline (273.487 us; speedup 1.0000x reference)
//
#include <hip/hip_runtime.h>

#define NCLS   32
#define SOS    30
#define EOS    31
#define NEGV   (-10000.0f)
#define LOG2E  1.4426950408889634f
#define LN2    0.6931471805599453f

// Split-j layout: 2 lanes per (batch, class). Wave = 1 batch (64 lanes =
// 32 classes x 2 halves). Block 256 = 4 batches; grid = B/4 = 512 blocks
// -> 2 blocks/CU -> 2 waves/SIMD (TLP to hide the serial chain latency;
// round-2 post-mortem: 1 wave/SIMD left the chain fully exposed).
//
// Each lane owns 16 transition coefficients, held as four explicit float4
// SSA locals (round-1/2 post-mortem: array alloca was demoted to scratch,
// VGPR_Count 36/52 proved it; scalars force register residency).
//
// Per step (log2 domain):
//   e = exp2(rel); wave writes 64 floats to its LDS row (both halves hold
//   identical rel -> two identical 32-float copies);
//   partial_h = sum over 16 owned j of ET[c][j] * e[j]  (4x ds_read_b128,
//   broadcast within each half, conflict-free);
//   dot = partial + shfl_xor(partial, 32);
//   rel = blend(m, fc + log2(dot), rel)   with fc = f*LOG2E + mT hoisted
//   into the prefetch ring (off the critical path).
// Re-center every 8 steps by wave lane 0; offset accumulates into C.
__global__ __launch_bounds__(256, 2) void crf_fwd(const float* __restrict__ feats,
                                                  const float* __restrict__ mask,
                                                  const float* __restrict__ trans,
                                                  float* __restrict__ out,
                                                  int S, int B) {
    __shared__ float e_sh[4 * 64];     // 4 waves/block, 64 floats each

    const int tid  = threadIdx.x;
    const int lane = tid & 63;
    const int wv   = tid >> 6;         // wave in block = batch in block
    const int c    = lane & 31;        // class
    const int h    = lane >> 5;        // j-half
    const int b    = blockIdx.x * 4 + wv;

    // ---- one-time: 16 coefficients of transition row c (half h) ----
    const float4* trow = (const float4*)(trans + c * NCLS + h * 16);
    float4 T0 = trow[0], T1 = trow[1], T2 = trow[2], T3 = trow[3];
    T0.x *= LOG2E; T0.y *= LOG2E; T0.z *= LOG2E; T0.w *= LOG2E;
    T1.x *= LOG2E; T1.y *= LOG2E; T1.z *= LOG2E; T1.w *= LOG2E;
    T2.x *= LOG2E; T2.y *= LOG2E; T2.z *= LOG2E; T2.w *= LOG2E;
    T3.x *= LOG2E; T3.y *= LOG2E; T3.z *= LOG2E; T3.w *= LOG2E;
    float mh = fmaxf(fmaxf(fmaxf(T0.x, T0.y), fmaxf(T0.z, T0.w)),
                     fmaxf(fmaxf(fmaxf(T1.x, T1.y), fmaxf(T1.z, T1.w)),
                           fmaxf(fmaxf(fmaxf(T2.x, T2.y), fmaxf(T2.z, T2.w)),
                                 fmaxf(fmaxf(T3.x, T3.y), fmaxf(T3.z, T3.w)))));
    const float mT = fmaxf(mh, __shfl_xor(mh, 32, 64));   // full-row max
    T0.x = __builtin_amdgcn_exp2f(T0.x - mT); T0.y = __builtin_amdgcn_exp2f(T0.y - mT);
    T0.z = __builtin_amdgcn_exp2f(T0.z - mT); T0.w = __builtin_amdgcn_exp2f(T0.w - mT);
    T1.x = __builtin_amdgcn_exp2f(T1.x - mT); T1.y = __builtin_amdgcn_exp2f(T1.y - mT);
    T1.z = __builtin_amdgcn_exp2f(T1.z - mT); T1.w = __builtin_amdgcn_exp2f(T1.w - mT);
    T2.x = __builtin_amdgcn_exp2f(T2.x - mT); T2.y = __builtin_amdgcn_exp2f(T2.y - mT);
    T2.z = __builtin_amdgcn_exp2f(T2.z - mT); T2.w = __builtin_amdgcn_exp2f(T2.w - mT);
    T3.x = __builtin_amdgcn_exp2f(T3.x - mT); T3.y = __builtin_amdgcn_exp2f(T3.y - mT);
    T3.z = __builtin_amdgcn_exp2f(T3.z - mT); T3.w = __builtin_amdgcn_exp2f(T3.w - mT);
    const float tEOSc = trans[EOS * NCLS + c] * LOG2E;    // T[EOS][c], scaled

    float* esh = e_sh + wv * 64;
    const float4* e4 = (const float4*)esh;
    const int qb = 12 * h;   // h=0 reads quads 0..3 of copy 0; h=1 quads 12..15 of copy 1

    // ---- init alpha0 (log2 domain): SOS=0, others -> exp2 == 0 ----
    float rel = (c == SOS) ? 0.0f : NEGV * LOG2E;
    float C = 0.0f;

    const size_t fstride = (size_t)B * NCLS;
    const float* fptr = feats + (size_t)b * NCLS + c;   // halves read same addr (merged)
    const float* mptr = mask + b;

    auto step = [&](float fc, float m) {
        const float e = __builtin_amdgcn_exp2f(rel);
        esh[lane] = e;                     // 64 consecutive floats: conflict-free
        __builtin_amdgcn_wave_barrier();
        const float4 v0 = e4[qb + 0], v1 = e4[qb + 1], v2 = e4[qb + 2], v3 = e4[qb + 3];
        float d0 = T0.x * v0.x, d1 = T0.y * v0.y, d2 = T0.z * v0.z, d3 = T0.w * v0.w;
        d0 = fmaf(T1.x, v1.x, d0); d1 = fmaf(T1.y, v1.y, d1);
        d2 = fmaf(T1.z, v1.z, d2); d3 = fmaf(T1.w, v1.w, d3);
        d0 = fmaf(T2.x, v2.x, d0); d1 = fmaf(T2.y, v2.y, d1);
        d2 = fmaf(T2.z, v2.z, d2); d3 = fmaf(T2.w, v2.w, d3);
        d0 = fmaf(T3.x, v3.x, d0); d1 = fmaf(T3.y, v3.y, d1);
        d2 = fmaf(T3.z, v3.z, d2); d3 = fmaf(T3.w, v3.w, d3);
        __builtin_amdgcn_wave_barrier();
        const float part = (d0 + d1) + (d2 + d3);
        const float dot  = part + __shfl_xor(part, 32, 64);   // combine halves
        const float rel_new = fc + __builtin_amdgcn_logf(dot);
        rel = fmaf(m, rel_new - rel, rel);  // mask blend (C offset common, valid)
    };

    float fb[8], mb[8];

    if (S >= 16) {
        #pragma unroll
        for (int i = 0; i < 8; ++i) {
            fb[i] = fmaf(fptr[(size_t)i * fstride], LOG2E, mT);
            mb[i] = mptr[(size_t)i * (size_t)B];
        }

        int tb = 0;
        // main loop: unconditional prefetch 8 ahead, strength-reduced pointers
        for (; tb + 16 <= S; tb += 8) {
            const float* fpp = fptr + (size_t)(tb + 8) * fstride;
            const float* mpp = mptr + (size_t)(tb + 8) * (size_t)B;
            #pragma unroll
            for (int u = 0; u < 8; ++u) {
                step(fb[u], mb[u]);
                fb[u] = fmaf(fpp[(size_t)u * fstride], LOG2E, mT);
                mb[u] = mpp[(size_t)u * (size_t)B];
            }
            const float D = __shfl(rel, 0, 64);   // re-center (wave lane 0)
            rel -= D; C += D;
        }
        // penultimate block: 8 steps with clamped (possibly dead) prefetch
        {
            #pragma unroll
            for (int u = 0; u < 8; ++u) {
                step(fb[u], mb[u]);
                int tp = tb + 8 + u; tp = (tp < S - 1) ? tp : (S - 1);
                fb[u] = fmaf(fptr[(size_t)tp * fstride], LOG2E, mT);
                mb[u] = mptr[(size_t)tp * (size_t)B];
            }
            const float D = __shfl(rel, 0, 64);
            rel -= D; C += D;
            tb += 8;
        }
        // tail: up to 7 remaining steps, static slots
        #pragma unroll
        for (int u = 0; u < 8; ++u) {
            if (tb + u < S) step(fb[u], mb[u]);
        }
    } else {
        for (int t = 0; t < S; ++t) {
            step(fmaf(fptr[(size_t)t * fstride], LOG2E, mT),
                 mptr[(size_t)t * (size_t)B]);
        }
    }

    // ---- epilogue: out[b] = ln2 * (C + log2(sum_c 2^(rel[c] + That[EOS][c]))) ----
    float v = (h == 0) ? __builtin_amdgcn_exp2f(rel + tEOSc) : 0.0f;
    #pragma unroll
    for (int off = 32; off; off >>= 1) v += __shfl_xor(v, off, 64);
    if (lane == 0) out[b] = LN2 * (C + __builtin_amdgcn_logf(v));
}

extern "C" void kernel_launch(void* const* d_in, const int* in_sizes, int n_in,
                              void* d_out, int out_size, void* d_ws, size_t ws_size,
                              hipStream_t stream) {
    const float* feats = (const float*)d_in[0];
    const float* mask  = (const float*)d_in[1];
    const float* trans = (const float*)d_in[2];
    float* out = (float*)d_out;

    const int B = out_size;            // batch  (2048)
    const int S = in_sizes[1] / B;     // seq_len (512)

    const int threads = B * NCLS * 2;  // 2 lanes per (batch, class)
    dim3 block(256);
    dim3 grid(threads / 256);
    hipLaunchKernelGGL(crf_fwd, grid, block, 0, stream, feats, mask, trans, out, S, B);
}